// Round 15
// baseline (151.582 us; speedup 1.0000x reference)
//
#include <hip/hip_runtime.h>
#include <hip/hip_bf16.h>

// x: (B=4, T=5, C=3, H=128, W=128) fp32 ; R=2 ; D = 60 ; N = 4096
#define BB 4
#define TC 15
#define DD 60
#define NN 4096
#define HH 128
#define DP 64
#define KT 64
#define NWAVE 4
#define QT 128
#define NTILES 64
#define NSPLIT 8
#define L2E 1.4426950408889634f

typedef short s8v __attribute__((ext_vector_type(8)));   // 8 x bf16
typedef ushort u4v __attribute__((ext_vector_type(4)));
typedef float f4v __attribute__((ext_vector_type(4)));
typedef float f2v __attribute__((ext_vector_type(2)));

static __device__ __forceinline__ ushort f2bf_bits(float f) {
    __hip_bfloat16 h = __float2bfloat16(f);
    return *reinterpret_cast<ushort*>(&h);
}
static __device__ __forceinline__ float bf2f_lo(uint u) { return __uint_as_float(u << 16); }
static __device__ __forceinline__ float bf2f_hi(uint u) { return __uint_as_float(u & 0xFFFF0000u); }
static __device__ __forceinline__ float bf2f(ushort w) { return __uint_as_float((uint)w << 16); }

// ---------- K1 (fused): x -> xf_bf (B,D,N) + xf_t (B,N,64) + rnorm + per-batch max norm ----------
__global__ __launch_bounds__(256) void k_prep(const float* __restrict__ x,
                                              ushort* __restrict__ xf_bf,
                                              ushort* __restrict__ xf_t,
                                              float* __restrict__ rnorm,
                                              uint* __restrict__ mxbits) {
    int ng = blockIdx.x * 256 + threadIdx.x;           // b*N + n (blocks never cross b)
    int b = ng >> 12, n = ng & (NN - 1);
    int oh = n >> 6, ow = n & 63;
    const float* xb = x + (size_t)b * TC * HH * HH;
    ushort* xbf = xf_bf + (size_t)b * DD * NN + n;
    ushort row[DP];
    float ss = 0.f;
    #pragma unroll
    for (int d = 0; d < DD; ++d) {
        int c1 = d >> 2, r1 = (d >> 1) & 1, r2 = d & 1;
        float v = xb[(c1 * HH + oh * 2 + r1) * HH + ow * 2 + r2];
        ushort w = f2bf_bits(v);
        row[d] = w;
        float f = bf2f(w);
        ss = fmaf(f, f, ss);
        xbf[(size_t)d * NN] = w;                       // coalesced across lanes
    }
    #pragma unroll
    for (int d = DD; d < DP; ++d) row[d] = 0;
    ushort* dst = xf_t + (size_t)ng * DP;
    #pragma unroll
    for (int j = 0; j < 8; ++j)
        *(s8v*)&dst[j * 8] = *(const s8v*)&row[j * 8];
    float norm = sqrtf(ss) * 1.0002f;                  // safety margin: m must bound row max
    rnorm[ng] = norm;
    float mv = norm;
    #pragma unroll
    for (int off = 1; off < 64; off <<= 1) mv = fmaxf(mv, __shfl_xor(mv, off));
    if ((threadIdx.x & 63) == 0) atomicMax(&mxbits[b], __float_as_uint(mv));
}

// ---------- K2: G (B,D,N) bf16 = g_w . xf + g_b, vec2 along n ----------
__global__ __launch_bounds__(256) void k_gproj(const ushort* __restrict__ xf_bf,
                                               const float* __restrict__ g_w,
                                               const float* __restrict__ g_b,
                                               ushort* __restrict__ G_bf) {
    int u = blockIdx.x * 256 + threadIdx.x;            // over elems/2
    int idx = u * 2;
    int n = idx & (NN - 1);
    int o = (idx >> 12) % DD;                          // block-uniform
    int b = idx / (DD * NN);
    const ushort* X = xf_bf + b * DD * NN;
    float a0 = g_b[o], a1 = a0;
    #pragma unroll
    for (int d = 0; d < DD; ++d) {
        uint w = *(const uint*)&X[d * NN + n];
        float gw = g_w[o * DD + d];
        a0 += gw * bf2f_lo(w);
        a1 += gw * bf2f_hi(w);
    }
    uint pack = (uint)f2bf_bits(a0) | ((uint)f2bf_bits(a1) << 16);
    *(uint*)&G_bf[idx] = pack;
}

// ---------- K3: flash attention, bf16 MFMA, fixed per-row softmax shift, split-K ----------
// Synthesis of r8-r14: latency/barrier-bound; controlling variable = resident blocks/CU.
// 256-thread (4-wave) blocks: smaller barrier scope + 4 blocks/CU (grid 1024, LDS 32KB).
// Keep r14's fragment hoisting: K/G frags read from LDS ONCE per tile, reused by both
// q-halves (32 q-rows per wave) -> ~14KB LDS traffic per 16 q-rows vs 24KB in r8.
// m_n = rnorm[n]*mxnorm[b] >= row max (Cauchy-Schwarz): no max tracking/rescale.
// l folded into PV via G row 60 == 1.0.
// __launch_bounds__(256,4): 128-VGPR cap, expected use ~90-110 (r14 measured 88).
template <int NS>
__global__ __launch_bounds__(256, 4) void k_attn(const ushort* __restrict__ xf_t,
                                                 const ushort* __restrict__ G_bf,
                                                 const float* __restrict__ rnorm,
                                                 const uint* __restrict__ mxbits,
                                                 ushort* __restrict__ Y_bf,    // NS==1
                                                 ushort* __restrict__ O_bf) {  // NS>1: (s,b,64,N) bf16
    __shared__ char K_lds[KT * 128];                   // 8 KB
    __shared__ char G_lds[DP * 128];                   // 8 KB
    __shared__ char P_lds[NWAVE][32 * 128];            // 16 KB

    int p = blockIdx.x;
    int s, b, q0;
    if (NS == NSPLIT) {
        // XCD-aware: xcd = p&7; each XCD pair-half owns one batch (4MB = one L2)
        int xcd = p & 7, slot = p >> 3;                // slot in [0,128)
        b = xcd >> 1;
        s = (xcd & 1) * 4 + (slot >> 5);
        q0 = (slot & 31) * QT;
    } else {
        s = 0;
        b = p >> 5;
        q0 = (p & 31) * QT;
    }
    int tid = threadIdx.x;
    int lane = tid & 63, wv = tid >> 6;
    int r = lane & 15, g = lane >> 4;

    const ushort* Xt = xf_t + (size_t)b * NN * DP;
    const ushort* Gb = G_bf + (size_t)b * DD * NN;

    // Q A-fragments: 2 halves x 2 k-blocks (16 VGPRs)
    s8v qa[2][2];
    #pragma unroll
    for (int h = 0; h < 2; ++h) {
        int qrow = q0 + wv * 32 + h * 16 + r;
        qa[h][0] = *(const s8v*)&Xt[(size_t)qrow * DP + g * 8];
        qa[h][1] = *(const s8v*)&Xt[(size_t)qrow * DP + 32 + g * 8];
    }

    // fixed per-row shift
    float mx = __uint_as_float(mxbits[b]);
    float nm[2][4];
    #pragma unroll
    for (int h = 0; h < 2; ++h)
        #pragma unroll
        for (int reg = 0; reg < 4; ++reg)
            nm[h][reg] = -rnorm[b * NN + q0 + wv * 32 + h * 16 + 4 * g + reg] * mx * L2E;

    f4v of[2][4];
    #pragma unroll
    for (int h = 0; h < 2; ++h)
        #pragma unroll
        for (int i = 0; i < 4; ++i) of[h][i] = (f4v){0.f, 0.f, 0.f, 0.f};

    // staging: 256 threads x two 16B units per buffer; row = e>>3, j = e&7
    const int e0 = tid, e1 = 256 + tid;
    const int kr0 = e0 >> 3, kj0 = e0 & 7;
    const int kr1 = e1 >> 3, kj1 = e1 & 7;
    const int kw0 = (kr0 * 128 + kj0 * 16) ^ ((kr0 & 7) << 4);
    const int kw1 = (kr1 * 128 + kj1 * 16) ^ ((kr1 & 7) << 4);
    const s8v ones8 = {(short)0x3F80, (short)0x3F80, (short)0x3F80, (short)0x3F80,
                       (short)0x3F80, (short)0x3F80, (short)0x3F80, (short)0x3F80};
    const s8v zero8 = {0, 0, 0, 0, 0, 0, 0, 0};
    s8v kp0, kp1, gp0, gp1;

    auto stage_regs = [&](int t) {
        int n0 = t * KT;
        kp0 = *(const s8v*)&Xt[(size_t)(n0 + kr0) * DP + kj0 * 8];
        kp1 = *(const s8v*)&Xt[(size_t)(n0 + kr1) * DP + kj1 * 8];
        gp0 = *(const s8v*)&Gb[(size_t)kr0 * NN + n0 + kj0 * 8];   // rows 0..31 < 60
        gp1 = (kr1 < DD) ? *(const s8v*)&Gb[(size_t)kr1 * NN + n0 + kj1 * 8]
                         : (kr1 == DD ? ones8 : zero8);
    };
    auto lds_write = [&]() {
        *(s8v*)(K_lds + kw0) = kp0;
        *(s8v*)(K_lds + kw1) = kp1;
        *(s8v*)(G_lds + kw0) = gp0;
        *(s8v*)(G_lds + kw1) = gp1;
    };

    const int t0 = s * (NTILES / NS);
    const int tend = t0 + NTILES / NS;
    char* Pw = P_lds[wv];

    stage_regs(t0);
    lds_write();
    __syncthreads();

    #pragma unroll 1
    for (int t = t0; t < tend; ++t) {
        bool more = (t + 1 < tend);
        if (more) stage_regs(t + 1);          // global loads in flight during compute

        // ---- hoisted K-fragments: read ONCE, feed both q-halves (32 VGPRs) ----
        s8v kf[8];
        #pragma unroll
        for (int kt2 = 0; kt2 < 4; ++kt2)
            #pragma unroll
            for (int kb = 0; kb < 2; ++kb) {
                int off = (((kt2 * 16 + r) * 128) + kb * 64 + g * 16) ^ ((r & 7) << 4);
                kf[kt2 * 2 + kb] = *(const s8v*)(K_lds + off);
            }

        // ---- QK + P per half (sf scoped -> dies before next half) ----
        #pragma unroll
        for (int h = 0; h < 2; ++h) {
            f4v sf[4];
            #pragma unroll
            for (int i = 0; i < 4; ++i) sf[i] = (f4v){0.f, 0.f, 0.f, 0.f};
            __builtin_amdgcn_s_setprio(1);
            #pragma unroll
            for (int kt2 = 0; kt2 < 4; ++kt2)
                #pragma unroll
                for (int kb = 0; kb < 2; ++kb)
                    sf[kt2] = __builtin_amdgcn_mfma_f32_16x16x32_bf16(
                        qa[h][kb], kf[kt2 * 2 + kb], sf[kt2], 0, 0, 0);
            __builtin_amdgcn_s_setprio(0);

            #pragma unroll
            for (int kt2 = 0; kt2 < 4; ++kt2)
                #pragma unroll
                for (int reg = 0; reg < 4; ++reg) {
                    float pv = __builtin_exp2f(fmaf(sf[kt2][reg], L2E, nm[h][reg]));
                    int row = h * 16 + 4 * g + reg;
                    int boff = ((row * 128) + kt2 * 32 + 2 * r) ^ ((row & 7) << 4);
                    *(ushort*)(Pw + boff) = f2bf_bits(pv);
                }
        }

        // ---- hoisted G-fragments: read ONCE, feed both halves (32 VGPRs) ----
        s8v gf[8];
        #pragma unroll
        for (int ot = 0; ot < 4; ++ot)
            #pragma unroll
            for (int kb = 0; kb < 2; ++kb) {
                int goff = (((ot * 16 + r) * 128) + kb * 64 + g * 16) ^ ((r & 7) << 4);
                gf[ot * 2 + kb] = *(const s8v*)(G_lds + goff);
            }

        // ---- PV per half (wave-internal P read; col 60 accumulates l) ----
        #pragma unroll
        for (int h = 0; h < 2; ++h) {
            __builtin_amdgcn_s_setprio(1);
            #pragma unroll
            for (int kb = 0; kb < 2; ++kb) {
                int prow = h * 16 + r;
                int poff = ((prow * 128) + kb * 64 + g * 16) ^ ((r & 7) << 4);
                s8v pa = *(const s8v*)(Pw + poff);
                #pragma unroll
                for (int ot = 0; ot < 4; ++ot)
                    of[h][ot] = __builtin_amdgcn_mfma_f32_16x16x32_bf16(
                        pa, gf[ot * 2 + kb], of[h][ot], 0, 0, 0);
            }
            __builtin_amdgcn_s_setprio(0);
        }

        __syncthreads();                      // all waves done reading K/G
        if (more) {
            lds_write();
            __syncthreads();                  // next tile staged
        }
    }

    if (NS == 1) {
        #pragma unroll
        for (int h = 0; h < 2; ++h) {
            int qb = q0 + wv * 32 + h * 16 + 4 * g;
            float linv[4];
            #pragma unroll
            for (int reg = 0; reg < 4; ++reg)
                linv[reg] = 1.0f / __shfl(of[h][3][reg], 12, 16);  // o=60 col holds l
            #pragma unroll
            for (int ot = 0; ot < 4; ++ot) {
                int o = ot * 16 + r;
                if (o < DD) {
                    #pragma unroll
                    for (int reg = 0; reg < 4; ++reg)
                        Y_bf[((size_t)(b * DD + o)) * NN + qb + reg] =
                            f2bf_bits(of[h][ot][reg] * linv[reg]);
                }
            }
        }
    } else {
        ushort* Ob = O_bf + ((size_t)(s * BB + b) * DP) * NN;
        #pragma unroll
        for (int h = 0; h < 2; ++h) {
            int qb = q0 + wv * 32 + h * 16 + 4 * g;
            #pragma unroll
            for (int ot = 0; ot < 4; ++ot) {
                int o = ot * 16 + r;
                u4v v = {f2bf_bits(of[h][ot][0]), f2bf_bits(of[h][ot][1]),
                         f2bf_bits(of[h][ot][2]), f2bf_bits(of[h][ot][3])};
                *(u4v*)&Ob[(size_t)o * NN + qb] = v;             // coalesced 32B per r-group
            }
        }
    }
}

// ---------- K3b: combine split partials (shared m -> plain sums) -> Y bf16 (B,D,N), vec2 ----------
__global__ __launch_bounds__(256) void k_combine(const ushort* __restrict__ O_bf,
                                                 ushort* __restrict__ Y_bf) {
    int u = blockIdx.x * 256 + threadIdx.x;            // over elems/2
    int idx = u * 2;
    int n = idx & (NN - 1);
    int o = (idx >> 12) % DD;
    int b = idx / (DD * NN);
    float a0 = 0.f, a1 = 0.f, L0 = 0.f, L1 = 0.f;
    #pragma unroll
    for (int s = 0; s < NSPLIT; ++s) {
        const ushort* Ob = O_bf + ((size_t)(s * BB + b) * DP) * NN + n;
        uint ov = *(const uint*)&Ob[(size_t)o * NN];
        uint lv = *(const uint*)&Ob[(size_t)DD * NN];
        a0 += bf2f_lo(ov); a1 += bf2f_hi(ov);
        L0 += bf2f_lo(lv); L1 += bf2f_hi(lv);
    }
    uint pack = (uint)f2bf_bits(a0 / L0) | ((uint)f2bf_bits(a1 / L1) << 16);
    *(uint*)&Y_bf[idx] = pack;
}

// ---------- K4: out = pixel_shuffle(w_w.Y + w_b) + x, pixel-major, vec2 over w ----------
__global__ __launch_bounds__(256) void k_out(const ushort* __restrict__ Y_bf,
                                             const float* __restrict__ w_w,
                                             const float* __restrict__ w_b,
                                             const float* __restrict__ x,
                                             float* __restrict__ out) {
    __shared__ float ww[DD * DD];
    __shared__ float wb[DD];
    for (int i = threadIdx.x; i < DD * DD; i += 256) ww[i] = w_w[i];
    if (threadIdx.x < DD) wb[threadIdx.x] = w_b[threadIdx.x];
    __syncthreads();
    int u = blockIdx.x * 256 + threadIdx.x;            // over B*TC*H*(W/2)
    int w2 = u & 63;
    int h = (u >> 6) & 127;
    int rest = u >> 13;
    int c1 = rest % TC;
    int b = rest / TC;
    int o0 = c1 * 4 + (h & 1) * 2;                     // wave-uniform
    int n = ((h >> 1) << 6) + w2;
    const ushort* Yb = Y_bf + (size_t)b * DD * NN + n;
    float a0 = wb[o0], a1 = wb[o0 + 1];
    #pragma unroll
    for (int d = 0; d < DD; ++d) {
        float y = bf2f(Yb[(size_t)d * NN]);
        a0 += ww[o0 * DD + d] * y;
        a1 += ww[(o0 + 1) * DD + d] * y;
    }
    size_t xi = ((size_t)(b * TC + c1) * HH + h) * HH + 2 * w2;
    f2v xv = *(const f2v*)&x[xi];
    f2v res = {a0 + xv[0], a1 + xv[1]};
    *(f2v*)&out[xi] = res;
}

extern "C" void kernel_launch(void* const* d_in, const int* in_sizes, int n_in,
                              void* d_out, int out_size, void* d_ws, size_t ws_size,
                              hipStream_t stream) {
    const float* x   = (const float*)d_in[0];
    const float* g_w = (const float*)d_in[1];
    const float* g_b = (const float*)d_in[2];
    const float* w_w = (const float*)d_in[3];
    const float* w_b = (const float*)d_in[4];
    float* out = (float*)d_out;

    char* ws = (char*)d_ws;
    ushort* xf_bf  = (ushort*)ws;                      // 1,966,080 B
    ushort* xf_t   = (ushort*)(ws + 1966080);          // 2,097,152 B
    ushort* G_bf   = (ushort*)(ws + 4063232);          // 1,966,080 B
    float*  rnorm  = (float*)(ws + 6029312);           // 65,536 B
    uint*   mxbits = (uint*)(ws + 6094848);            // 256 B (16 used)
    ushort* O_bf   = (ushort*)(ws + 6095104);          // 16,777,216 B -> end 22,872,320
    const size_t SPLIT_NEED = 22872320;

    hipMemsetAsync(mxbits, 0, BB * sizeof(uint), stream);
    k_prep<<<BB * NN / 256, 256, 0, stream>>>(x, xf_bf, xf_t, rnorm, mxbits);
    k_gproj<<<1920, 256, 0, stream>>>(xf_bf, g_w, g_b, G_bf);

    ushort* Y_bf;
    if (ws_size >= SPLIT_NEED) {
        k_attn<NSPLIT><<<NSPLIT * BB * (NN / QT), 256, 0, stream>>>(
            xf_t, G_bf, rnorm, mxbits, nullptr, O_bf);
        Y_bf = (ushort*)ws;                            // alias xf_bf (dead after attn)
        k_combine<<<1920, 256, 0, stream>>>(O_bf, Y_bf);
    } else {
        Y_bf = (ushort*)(ws + 6095104);
        k_attn<1><<<BB * (NN / QT), 256, 0, stream>>>(
            xf_t, G_bf, rnorm, mxbits, Y_bf, nullptr);
    }
    k_out<<<1920, 256, 0, stream>>>(Y_bf, w_w, w_b, x, out);
}

// Round 16
// 98.031 us; speedup vs baseline: 1.5463x; 1.5463x over previous
//
#include <hip/hip_runtime.h>
#include <hip/hip_bf16.h>

// x: (B=4, T=5, C=3, H=128, W=128) fp32 ; R=2 ; D = 60 ; N = 4096
#define BB 4
#define TC 15
#define DD 60
#define NN 4096
#define HH 128
#define DP 64
#define KT 64
#define NWAVE 8
#define QT 128
#define NTILES 64
#define NSPLIT 8
#define L2E 1.4426950408889634f

typedef short s8v __attribute__((ext_vector_type(8)));   // 8 x bf16
typedef ushort u4v __attribute__((ext_vector_type(4)));
typedef float f4v __attribute__((ext_vector_type(4)));
typedef float f2v __attribute__((ext_vector_type(2)));

static __device__ __forceinline__ ushort f2bf_bits(float f) {
    __hip_bfloat16 h = __float2bfloat16(f);
    return *reinterpret_cast<ushort*>(&h);
}
static __device__ __forceinline__ float bf2f_lo(uint u) { return __uint_as_float(u << 16); }
static __device__ __forceinline__ float bf2f_hi(uint u) { return __uint_as_float(u & 0xFFFF0000u); }
static __device__ __forceinline__ float bf2f(ushort w) { return __uint_as_float((uint)w << 16); }

// ---------- K1 (fused): x -> xf_t (B,N,64) + G_bf (B,D,N) + rnorm + per-batch max norm ----------
// One thread per pixel (b,n): holds the 60-vector in registers, so the g-projection
// G[:,n] = g_w . row + g_b happens here (g_w indices are wave-uniform -> scalar loads).
// Eliminates the xf_bf buffer and the separate k_gproj pass entirely.
__global__ __launch_bounds__(64) void k_prep(const float* __restrict__ x,
                                             ushort* __restrict__ xf_t,
                                             ushort* __restrict__ G_bf,
                                             const float* __restrict__ g_w,
                                             const float* __restrict__ g_b,
                                             float* __restrict__ rnorm,
                                             uint* __restrict__ mxbits) {
    int ng = blockIdx.x * 64 + threadIdx.x;            // b*N + n
    int b = ng >> 12, n = ng & (NN - 1);
    int oh = n >> 6, ow = n & 63;
    const float* xb = x + (size_t)b * TC * HH * HH;
    float rowf[DD];
    ushort rowb[DP];
    float ss = 0.f;
    #pragma unroll
    for (int d = 0; d < DD; ++d) {
        int c1 = d >> 2, r1 = (d >> 1) & 1, r2 = d & 1;
        float v = xb[(c1 * HH + oh * 2 + r1) * HH + ow * 2 + r2];
        ushort w = f2bf_bits(v);
        rowb[d] = w;
        float f = bf2f(w);
        rowf[d] = f;
        ss = fmaf(f, f, ss);
    }
    #pragma unroll
    for (int d = DD; d < DP; ++d) rowb[d] = 0;
    ushort* dst = xf_t + (size_t)ng * DP;
    #pragma unroll
    for (int j = 0; j < 8; ++j)
        *(s8v*)&dst[j * 8] = *(const s8v*)&rowb[j * 8];
    float norm = sqrtf(ss) * 1.0002f;                  // safety margin: m must bound row max
    rnorm[ng] = norm;
    float mv = norm;
    #pragma unroll
    for (int off = 1; off < 64; off <<= 1) mv = fmaxf(mv, __shfl_xor(mv, off));
    if (threadIdx.x == 0) atomicMax(&mxbits[b], __float_as_uint(mv));

    // G projection: o,d indices wave-uniform -> g_w/g_b scalarize to s_loads
    ushort* Gp = G_bf + (size_t)b * DD * NN + n;
    for (int o = 0; o < DD; ++o) {
        float acc = g_b[o];
        #pragma unroll
        for (int d = 0; d < DD; ++d)
            acc = fmaf(g_w[o * DD + d], rowf[d], acc);
        Gp[(size_t)o * NN] = f2bf_bits(acc);           // coalesced across lanes
    }
}

// ---------- K3: flash attention (EXACT round-11 structure: QT=128, 8 waves, dbuf,
// one barrier/tile, P/PV interleave; proven 43.5 us). bf16 MFMA, fixed per-row
// softmax shift m_n = rnorm[n]*mxnorm[b] (Cauchy-Schwarz upper bound): no max
// tracking, no rescale. l folded into PV via G row 60 == 1.0.
// __launch_bounds__(512,4): allocator caps arch-VGPR at 64; this kernel uses 52.
template <int NS>
__global__ __launch_bounds__(512, 4) void k_attn(const ushort* __restrict__ xf_t,
                                                 const ushort* __restrict__ G_bf,
                                                 const float* __restrict__ rnorm,
                                                 const uint* __restrict__ mxbits,
                                                 ushort* __restrict__ Y_bf,    // NS==1
                                                 ushort* __restrict__ O_bf) {  // NS>1: (s,b,64,N) bf16
    __shared__ char K_lds[2][KT * 128];
    __shared__ char G_lds[2][DP * 128];
    __shared__ char P_lds[NWAVE][16 * 128];

    int p = blockIdx.x;
    int s, b, q0;
    if (NS == NSPLIT) {
        // XCD-aware: xcd = p&7; each XCD pair-half owns one batch (4MB = one L2)
        int xcd = p & 7, slot = p >> 3;                // slot in [0,128)
        b = xcd >> 1;
        s = (xcd & 1) * 4 + (slot >> 5);
        q0 = (slot & 31) * QT;
    } else {
        s = 0;
        b = p >> 5;
        q0 = (p & 31) * QT;
    }
    int tid = threadIdx.x;
    int lane = tid & 63, wv = tid >> 6;
    int r = lane & 15, g = lane >> 4;

    const ushort* Xt = xf_t + (size_t)b * NN * DP;
    const ushort* Gb = G_bf + (size_t)b * DD * NN;

    int qrow = q0 + wv * 16 + r;
    s8v qa[2];
    qa[0] = *(const s8v*)&Xt[(size_t)qrow * DP + g * 8];
    qa[1] = *(const s8v*)&Xt[(size_t)qrow * DP + 32 + g * 8];

    // fixed per-row shift, rows 4g+0..3 of this lane
    float mx = __uint_as_float(mxbits[b]);
    float nm[4];
    #pragma unroll
    for (int reg = 0; reg < 4; ++reg)
        nm[reg] = -rnorm[b * NN + q0 + wv * 16 + 4 * g + reg] * mx * L2E;

    f4v of[4];
    #pragma unroll
    for (int i = 0; i < 4; ++i) of[i] = (f4v){0.f, 0.f, 0.f, 0.f};

    // staging: 512 threads x one 16B unit each per buffer; row = tid>>3, j = tid&7
    const int kr0 = tid >> 3, kj0 = tid & 7;
    const int kw0 = (kr0 * 128 + kj0 * 16) ^ ((kr0 & 7) << 4);
    const s8v ones8 = {(short)0x3F80, (short)0x3F80, (short)0x3F80, (short)0x3F80,
                       (short)0x3F80, (short)0x3F80, (short)0x3F80, (short)0x3F80};
    const s8v zero8 = {0, 0, 0, 0, 0, 0, 0, 0};
    s8v kp0, gp0;

    auto stage_regs = [&](int t) {
        int n0 = t * KT;
        kp0 = *(const s8v*)&Xt[(size_t)(n0 + kr0) * DP + kj0 * 8];
        gp0 = (kr0 < DD) ? *(const s8v*)&Gb[(size_t)kr0 * NN + n0 + kj0 * 8]
                         : (kr0 == DD ? ones8 : zero8);
    };
    auto lds_write = [&](int bu) {
        *(s8v*)(K_lds[bu] + kw0) = kp0;
        *(s8v*)(G_lds[bu] + kw0) = gp0;
    };

    const int t0 = s * (NTILES / NS);
    const int tend = t0 + NTILES / NS;
    char* Pw = P_lds[wv];

    stage_regs(t0);
    lds_write(0);
    __syncthreads();

    #pragma unroll 1
    for (int t = t0; t < tend; ++t) {
        const int cur = (t - t0) & 1;
        bool more = (t + 1 < tend);
        if (more) stage_regs(t + 1);          // global loads in flight during compute
        const char* Kc = K_lds[cur];
        const char* Gc = G_lds[cur];

        // ---- S = Q.K^T ----
        f4v sf[4];
        #pragma unroll
        for (int i = 0; i < 4; ++i) sf[i] = (f4v){0.f, 0.f, 0.f, 0.f};
        __builtin_amdgcn_s_setprio(1);
        #pragma unroll
        for (int kt2 = 0; kt2 < 4; ++kt2)
            #pragma unroll
            for (int kb = 0; kb < 2; ++kb) {
                int off = (((kt2 * 16 + r) * 128) + kb * 64 + g * 16) ^ ((r & 7) << 4);
                s8v bf = *(const s8v*)(Kc + off);
                sf[kt2] = __builtin_amdgcn_mfma_f32_16x16x32_bf16(qa[kb], bf, sf[kt2], 0, 0, 0);
            }
        __builtin_amdgcn_s_setprio(0);

        // ---- P for keys 0..31 (kt2 = 0,1) ----
        #pragma unroll
        for (int kt2 = 0; kt2 < 2; ++kt2)
            #pragma unroll
            for (int reg = 0; reg < 4; ++reg) {
                float pv = __builtin_exp2f(fmaf(sf[kt2][reg], L2E, nm[reg]));
                int row = 4 * g + reg;
                int boff = ((row * 128) + kt2 * 32 + 2 * r) ^ ((row & 7) << 4);
                *(ushort*)(Pw + boff) = f2bf_bits(pv);
            }
        // ---- PV kb=0 (wave-internal LDS is in-order; overlaps next P block) ----
        {
            int poff = ((r * 128) + g * 16) ^ ((r & 7) << 4);
            s8v pa = *(const s8v*)(Pw + poff);
            __builtin_amdgcn_s_setprio(1);
            #pragma unroll
            for (int ot = 0; ot < 4; ++ot) {
                int goff = (((ot * 16 + r) * 128) + g * 16) ^ ((r & 7) << 4);
                s8v gf = *(const s8v*)(Gc + goff);
                of[ot] = __builtin_amdgcn_mfma_f32_16x16x32_bf16(pa, gf, of[ot], 0, 0, 0);
            }
            __builtin_amdgcn_s_setprio(0);
        }
        // ---- P for keys 32..63 (kt2 = 2,3) ----
        #pragma unroll
        for (int kt2 = 2; kt2 < 4; ++kt2)
            #pragma unroll
            for (int reg = 0; reg < 4; ++reg) {
                float pv = __builtin_exp2f(fmaf(sf[kt2][reg], L2E, nm[reg]));
                int row = 4 * g + reg;
                int boff = ((row * 128) + kt2 * 32 + 2 * r) ^ ((row & 7) << 4);
                *(ushort*)(Pw + boff) = f2bf_bits(pv);
            }
        // ---- PV kb=1 ----
        {
            int poff = ((r * 128) + 64 + g * 16) ^ ((r & 7) << 4);
            s8v pa = *(const s8v*)(Pw + poff);
            __builtin_amdgcn_s_setprio(1);
            #pragma unroll
            for (int ot = 0; ot < 4; ++ot) {
                int goff = (((ot * 16 + r) * 128) + 64 + g * 16) ^ ((r & 7) << 4);
                s8v gf = *(const s8v*)(Gc + goff);
                of[ot] = __builtin_amdgcn_mfma_f32_16x16x32_bf16(pa, gf, of[ot], 0, 0, 0);
            }
            __builtin_amdgcn_s_setprio(0);
        }

        if (more) lds_write(cur ^ 1);         // write-late into the other buffer
        __syncthreads();                      // single barrier per tile
    }

    int qb = q0 + wv * 16 + 4 * g;
    if (NS == 1) {
        float linv[4];
        #pragma unroll
        for (int reg = 0; reg < 4; ++reg)
            linv[reg] = 1.0f / __shfl(of[3][reg], 12, 16);   // o=60 column holds l
        #pragma unroll
        for (int ot = 0; ot < 4; ++ot) {
            int o = ot * 16 + r;
            if (o < DD) {
                #pragma unroll
                for (int reg = 0; reg < 4; ++reg)
                    Y_bf[((size_t)(b * DD + o)) * NN + qb + reg] =
                        f2bf_bits(of[ot][reg] * linv[reg]);
            }
        }
    } else {
        ushort* Ob = O_bf + ((size_t)(s * BB + b) * DP) * NN;
        #pragma unroll
        for (int ot = 0; ot < 4; ++ot) {
            int o = ot * 16 + r;
            u4v v = {f2bf_bits(of[ot][0]), f2bf_bits(of[ot][1]),
                     f2bf_bits(of[ot][2]), f2bf_bits(of[ot][3])};
            *(u4v*)&Ob[(size_t)o * NN + qb] = v;                 // coalesced 32B per r-group
        }
    }
}

// ---------- K3b: combine split partials (shared m -> plain sums) -> Y bf16 (B,D,N), vec2 ----------
__global__ __launch_bounds__(256) void k_combine(const ushort* __restrict__ O_bf,
                                                 ushort* __restrict__ Y_bf) {
    int u = blockIdx.x * 256 + threadIdx.x;            // over elems/2
    int idx = u * 2;
    int n = idx & (NN - 1);
    int o = (idx >> 12) % DD;
    int b = idx / (DD * NN);
    float a0 = 0.f, a1 = 0.f, L0 = 0.f, L1 = 0.f;
    #pragma unroll
    for (int s = 0; s < NSPLIT; ++s) {
        const ushort* Ob = O_bf + ((size_t)(s * BB + b) * DP) * NN + n;
        uint ov = *(const uint*)&Ob[(size_t)o * NN];
        uint lv = *(const uint*)&Ob[(size_t)DD * NN];
        a0 += bf2f_lo(ov); a1 += bf2f_hi(ov);
        L0 += bf2f_lo(lv); L1 += bf2f_hi(lv);
    }
    uint pack = (uint)f2bf_bits(a0 / L0) | ((uint)f2bf_bits(a1 / L1) << 16);
    *(uint*)&Y_bf[idx] = pack;
}

// ---------- K4: out = pixel_shuffle(w_w.Y + w_b) + x, pixel-major, vec2 over w ----------
__global__ __launch_bounds__(256) void k_out(const ushort* __restrict__ Y_bf,
                                             const float* __restrict__ w_w,
                                             const float* __restrict__ w_b,
                                             const float* __restrict__ x,
                                             float* __restrict__ out) {
    __shared__ float ww[DD * DD];
    __shared__ float wb[DD];
    for (int i = threadIdx.x; i < DD * DD; i += 256) ww[i] = w_w[i];
    if (threadIdx.x < DD) wb[threadIdx.x] = w_b[threadIdx.x];
    __syncthreads();
    int u = blockIdx.x * 256 + threadIdx.x;            // over B*TC*H*(W/2)
    int w2 = u & 63;
    int h = (u >> 6) & 127;
    int rest = u >> 13;
    int c1 = rest % TC;
    int b = rest / TC;
    int o0 = c1 * 4 + (h & 1) * 2;                     // wave-uniform
    int n = ((h >> 1) << 6) + w2;
    const ushort* Yb = Y_bf + (size_t)b * DD * NN + n;
    float a0 = wb[o0], a1 = wb[o0 + 1];
    #pragma unroll
    for (int d = 0; d < DD; ++d) {
        float y = bf2f(Yb[(size_t)d * NN]);
        a0 += ww[o0 * DD + d] * y;
        a1 += ww[(o0 + 1) * DD + d] * y;
    }
    size_t xi = ((size_t)(b * TC + c1) * HH + h) * HH + 2 * w2;
    f2v xv = *(const f2v*)&x[xi];
    f2v res = {a0 + xv[0], a1 + xv[1]};
    *(f2v*)&out[xi] = res;
}

extern "C" void kernel_launch(void* const* d_in, const int* in_sizes, int n_in,
                              void* d_out, int out_size, void* d_ws, size_t ws_size,
                              hipStream_t stream) {
    const float* x   = (const float*)d_in[0];
    const float* g_w = (const float*)d_in[1];
    const float* g_b = (const float*)d_in[2];
    const float* w_w = (const float*)d_in[3];
    const float* w_b = (const float*)d_in[4];
    float* out = (float*)d_out;

    char* ws = (char*)d_ws;
    ushort* xf_t   = (ushort*)ws;                      // 2,097,152 B
    ushort* G_bf   = (ushort*)(ws + 2097152);          // 1,966,080 B
    float*  rnorm  = (float*)(ws + 4063232);           // 65,536 B
    uint*   mxbits = (uint*)(ws + 4128768);            // 256 B (16 used)
    ushort* O_bf   = (ushort*)(ws + 4129024);          // 16,777,216 B -> end 20,906,240
    const size_t SPLIT_NEED = 20906240;

    hipMemsetAsync(mxbits, 0, BB * sizeof(uint), stream);
    k_prep<<<BB * NN / 64, 64, 0, stream>>>(x, xf_t, G_bf, g_w, g_b, rnorm, mxbits);

    ushort* Y_bf;
    if (ws_size >= SPLIT_NEED) {
        k_attn<NSPLIT><<<NSPLIT * BB * (NN / QT), 512, 0, stream>>>(
            xf_t, G_bf, rnorm, mxbits, nullptr, O_bf);
        Y_bf = (ushort*)ws;                            // alias xf_t (dead after attn)
        k_combine<<<1920, 256, 0, stream>>>(O_bf, Y_bf);
    } else {
        Y_bf = (ushort*)(ws + 4129024);
        k_attn<1><<<BB * (NN / QT), 512, 0, stream>>>(
            xf_t, G_bf, rnorm, mxbits, Y_bf, nullptr);
    }
    k_out<<<1920, 256, 0, stream>>>(Y_bf, w_w, w_b, x, out);
}

// Round 17
// 80.134 us; speedup vs baseline: 1.8916x; 1.2233x over previous
//
#include <hip/hip_runtime.h>
#include <hip/hip_bf16.h>

// x: (B=4, T=5, C=3, H=128, W=128) fp32 ; R=2 ; D = 60 ; N = 4096
#define BB 4
#define TC 15
#define DD 60
#define NN 4096
#define HH 128
#define DP 64
#define KT 64
#define NWAVE 8
#define QT 128
#define NTILES 64
#define NSPLIT 8
#define L2E 1.4426950408889634f

typedef short s8v __attribute__((ext_vector_type(8)));   // 8 x bf16
typedef ushort u4v __attribute__((ext_vector_type(4)));
typedef float f4v __attribute__((ext_vector_type(4)));
typedef float f2v __attribute__((ext_vector_type(2)));

static __device__ __forceinline__ ushort f2bf_bits(float f) {
    __hip_bfloat16 h = __float2bfloat16(f);
    return *reinterpret_cast<ushort*>(&h);
}
static __device__ __forceinline__ float bf2f_lo(uint u) { return __uint_as_float(u << 16); }
static __device__ __forceinline__ float bf2f_hi(uint u) { return __uint_as_float(u & 0xFFFF0000u); }
static __device__ __forceinline__ float bf2f(ushort w) { return __uint_as_float((uint)w << 16); }

// ---------- K1: x -> xf_bf (B,D,N) + xf_t (B,N,64) + rnorm + per-batch max norm ----------
// (r12 structure: parallel streaming, no long dependent chains — the r15/r16 gproj
// fusion ran at 1 wave/CU with a 3600-FMA serial chain and cost 46 us; reverted.)
__global__ __launch_bounds__(256) void k_prep(const float* __restrict__ x,
                                              ushort* __restrict__ xf_bf,
                                              ushort* __restrict__ xf_t,
                                              float* __restrict__ rnorm,
                                              uint* __restrict__ mxbits) {
    int ng = blockIdx.x * 256 + threadIdx.x;           // b*N + n (blocks never cross b)
    int b = ng >> 12, n = ng & (NN - 1);
    int oh = n >> 6, ow = n & 63;
    const float* xb = x + (size_t)b * TC * HH * HH;
    ushort* xbf = xf_bf + (size_t)b * DD * NN + n;
    ushort row[DP];
    float ss = 0.f;
    #pragma unroll
    for (int d = 0; d < DD; ++d) {
        int c1 = d >> 2, r1 = (d >> 1) & 1, r2 = d & 1;
        float v = xb[(c1 * HH + oh * 2 + r1) * HH + ow * 2 + r2];
        ushort w = f2bf_bits(v);
        row[d] = w;
        float f = bf2f(w);
        ss = fmaf(f, f, ss);
        xbf[(size_t)d * NN] = w;                       // coalesced across lanes
    }
    #pragma unroll
    for (int d = DD; d < DP; ++d) row[d] = 0;
    ushort* dst = xf_t + (size_t)ng * DP;
    #pragma unroll
    for (int j = 0; j < 8; ++j)
        *(s8v*)&dst[j * 8] = *(const s8v*)&row[j * 8];
    float norm = sqrtf(ss) * 1.0002f;                  // safety margin: m must bound row max
    rnorm[ng] = norm;
    float mv = norm;
    #pragma unroll
    for (int off = 1; off < 64; off <<= 1) mv = fmaxf(mv, __shfl_xor(mv, off));
    if ((threadIdx.x & 63) == 0) atomicMax(&mxbits[b], __float_as_uint(mv));
}

// ---------- K2: G (B,D,N) bf16 = g_w . xf + g_b, vec2 along n ----------
__global__ __launch_bounds__(256) void k_gproj(const ushort* __restrict__ xf_bf,
                                               const float* __restrict__ g_w,
                                               const float* __restrict__ g_b,
                                               ushort* __restrict__ G_bf) {
    int u = blockIdx.x * 256 + threadIdx.x;            // over elems/2
    int idx = u * 2;
    int n = idx & (NN - 1);
    int o = (idx >> 12) % DD;                          // block-uniform
    int b = idx / (DD * NN);
    const ushort* X = xf_bf + b * DD * NN;
    float a0 = g_b[o], a1 = a0;
    #pragma unroll
    for (int d = 0; d < DD; ++d) {
        uint w = *(const uint*)&X[d * NN + n];
        float gw = g_w[o * DD + d];
        a0 += gw * bf2f_lo(w);
        a1 += gw * bf2f_hi(w);
    }
    uint pack = (uint)f2bf_bits(a0) | ((uint)f2bf_bits(a1) << 16);
    *(uint*)&G_bf[idx] = pack;
}

// ---------- K3: flash attention (EXACT round-11 structure: QT=128, 8 waves, dbuf,
// one barrier/tile, P/PV interleave; proven 43.5 us). bf16 MFMA, fixed per-row
// softmax shift m_n = rnorm[n]*mxnorm[b] (Cauchy-Schwarz upper bound): no max
// tracking, no rescale. l folded into PV via G row 60 == 1.0.
// __launch_bounds__(512,4): allocator caps arch-VGPR at 64; this kernel uses 52.
template <int NS>
__global__ __launch_bounds__(512, 4) void k_attn(const ushort* __restrict__ xf_t,
                                                 const ushort* __restrict__ G_bf,
                                                 const float* __restrict__ rnorm,
                                                 const uint* __restrict__ mxbits,
                                                 ushort* __restrict__ Y_bf,    // NS==1
                                                 ushort* __restrict__ O_bf) {  // NS>1: (s,b,64,N) bf16
    __shared__ char K_lds[2][KT * 128];
    __shared__ char G_lds[2][DP * 128];
    __shared__ char P_lds[NWAVE][16 * 128];

    int p = blockIdx.x;
    int s, b, q0;
    if (NS == NSPLIT) {
        // XCD-aware: xcd = p&7; each XCD pair-half owns one batch (4MB = one L2)
        int xcd = p & 7, slot = p >> 3;                // slot in [0,128)
        b = xcd >> 1;
        s = (xcd & 1) * 4 + (slot >> 5);
        q0 = (slot & 31) * QT;
    } else {
        s = 0;
        b = p >> 5;
        q0 = (p & 31) * QT;
    }
    int tid = threadIdx.x;
    int lane = tid & 63, wv = tid >> 6;
    int r = lane & 15, g = lane >> 4;

    const ushort* Xt = xf_t + (size_t)b * NN * DP;
    const ushort* Gb = G_bf + (size_t)b * DD * NN;

    int qrow = q0 + wv * 16 + r;
    s8v qa[2];
    qa[0] = *(const s8v*)&Xt[(size_t)qrow * DP + g * 8];
    qa[1] = *(const s8v*)&Xt[(size_t)qrow * DP + 32 + g * 8];

    // fixed per-row shift, rows 4g+0..3 of this lane
    float mx = __uint_as_float(mxbits[b]);
    float nm[4];
    #pragma unroll
    for (int reg = 0; reg < 4; ++reg)
        nm[reg] = -rnorm[b * NN + q0 + wv * 16 + 4 * g + reg] * mx * L2E;

    f4v of[4];
    #pragma unroll
    for (int i = 0; i < 4; ++i) of[i] = (f4v){0.f, 0.f, 0.f, 0.f};

    // staging: 512 threads x one 16B unit each per buffer; row = tid>>3, j = tid&7
    const int kr0 = tid >> 3, kj0 = tid & 7;
    const int kw0 = (kr0 * 128 + kj0 * 16) ^ ((kr0 & 7) << 4);
    const s8v ones8 = {(short)0x3F80, (short)0x3F80, (short)0x3F80, (short)0x3F80,
                       (short)0x3F80, (short)0x3F80, (short)0x3F80, (short)0x3F80};
    const s8v zero8 = {0, 0, 0, 0, 0, 0, 0, 0};
    s8v kp0, gp0;

    auto stage_regs = [&](int t) {
        int n0 = t * KT;
        kp0 = *(const s8v*)&Xt[(size_t)(n0 + kr0) * DP + kj0 * 8];
        gp0 = (kr0 < DD) ? *(const s8v*)&Gb[(size_t)kr0 * NN + n0 + kj0 * 8]
                         : (kr0 == DD ? ones8 : zero8);
    };
    auto lds_write = [&](int bu) {
        *(s8v*)(K_lds[bu] + kw0) = kp0;
        *(s8v*)(G_lds[bu] + kw0) = gp0;
    };

    const int t0 = s * (NTILES / NS);
    const int tend = t0 + NTILES / NS;
    char* Pw = P_lds[wv];

    stage_regs(t0);
    lds_write(0);
    __syncthreads();

    #pragma unroll 1
    for (int t = t0; t < tend; ++t) {
        const int cur = (t - t0) & 1;
        bool more = (t + 1 < tend);
        if (more) stage_regs(t + 1);          // global loads in flight during compute
        const char* Kc = K_lds[cur];
        const char* Gc = G_lds[cur];

        // ---- S = Q.K^T ----
        f4v sf[4];
        #pragma unroll
        for (int i = 0; i < 4; ++i) sf[i] = (f4v){0.f, 0.f, 0.f, 0.f};
        __builtin_amdgcn_s_setprio(1);
        #pragma unroll
        for (int kt2 = 0; kt2 < 4; ++kt2)
            #pragma unroll
            for (int kb = 0; kb < 2; ++kb) {
                int off = (((kt2 * 16 + r) * 128) + kb * 64 + g * 16) ^ ((r & 7) << 4);
                s8v bf = *(const s8v*)(Kc + off);
                sf[kt2] = __builtin_amdgcn_mfma_f32_16x16x32_bf16(qa[kb], bf, sf[kt2], 0, 0, 0);
            }
        __builtin_amdgcn_s_setprio(0);

        // ---- P for keys 0..31 (kt2 = 0,1) ----
        #pragma unroll
        for (int kt2 = 0; kt2 < 2; ++kt2)
            #pragma unroll
            for (int reg = 0; reg < 4; ++reg) {
                float pv = __builtin_exp2f(fmaf(sf[kt2][reg], L2E, nm[reg]));
                int row = 4 * g + reg;
                int boff = ((row * 128) + kt2 * 32 + 2 * r) ^ ((row & 7) << 4);
                *(ushort*)(Pw + boff) = f2bf_bits(pv);
            }
        // ---- PV kb=0 (wave-internal LDS is in-order; overlaps next P block) ----
        {
            int poff = ((r * 128) + g * 16) ^ ((r & 7) << 4);
            s8v pa = *(const s8v*)(Pw + poff);
            __builtin_amdgcn_s_setprio(1);
            #pragma unroll
            for (int ot = 0; ot < 4; ++ot) {
                int goff = (((ot * 16 + r) * 128) + g * 16) ^ ((r & 7) << 4);
                s8v gf = *(const s8v*)(Gc + goff);
                of[ot] = __builtin_amdgcn_mfma_f32_16x16x32_bf16(pa, gf, of[ot], 0, 0, 0);
            }
            __builtin_amdgcn_s_setprio(0);
        }
        // ---- P for keys 32..63 (kt2 = 2,3) ----
        #pragma unroll
        for (int kt2 = 2; kt2 < 4; ++kt2)
            #pragma unroll
            for (int reg = 0; reg < 4; ++reg) {
                float pv = __builtin_exp2f(fmaf(sf[kt2][reg], L2E, nm[reg]));
                int row = 4 * g + reg;
                int boff = ((row * 128) + kt2 * 32 + 2 * r) ^ ((row & 7) << 4);
                *(ushort*)(Pw + boff) = f2bf_bits(pv);
            }
        // ---- PV kb=1 ----
        {
            int poff = ((r * 128) + 64 + g * 16) ^ ((r & 7) << 4);
            s8v pa = *(const s8v*)(Pw + poff);
            __builtin_amdgcn_s_setprio(1);
            #pragma unroll
            for (int ot = 0; ot < 4; ++ot) {
                int goff = (((ot * 16 + r) * 128) + 64 + g * 16) ^ ((r & 7) << 4);
                s8v gf = *(const s8v*)(Gc + goff);
                of[ot] = __builtin_amdgcn_mfma_f32_16x16x32_bf16(pa, gf, of[ot], 0, 0, 0);
            }
            __builtin_amdgcn_s_setprio(0);
        }

        if (more) lds_write(cur ^ 1);         // write-late into the other buffer
        __syncthreads();                      // single barrier per tile
    }

    int qb = q0 + wv * 16 + 4 * g;
    if (NS == 1) {
        float linv[4];
        #pragma unroll
        for (int reg = 0; reg < 4; ++reg)
            linv[reg] = 1.0f / __shfl(of[3][reg], 12, 16);   // o=60 column holds l
        #pragma unroll
        for (int ot = 0; ot < 4; ++ot) {
            int o = ot * 16 + r;
            if (o < DD) {
                #pragma unroll
                for (int reg = 0; reg < 4; ++reg)
                    Y_bf[((size_t)(b * DD + o)) * NN + qb + reg] =
                        f2bf_bits(of[ot][reg] * linv[reg]);
            }
        }
    } else {
        ushort* Ob = O_bf + ((size_t)(s * BB + b) * DP) * NN;
        #pragma unroll
        for (int ot = 0; ot < 4; ++ot) {
            int o = ot * 16 + r;
            u4v v = {f2bf_bits(of[ot][0]), f2bf_bits(of[ot][1]),
                     f2bf_bits(of[ot][2]), f2bf_bits(of[ot][3])};
            *(u4v*)&Ob[(size_t)o * NN + qb] = v;                 // coalesced 32B per r-group
        }
    }
}

// ---------- K3b: combine split partials (shared m -> plain sums) -> Y bf16 (B,D,N), vec2 ----------
__global__ __launch_bounds__(256) void k_combine(const ushort* __restrict__ O_bf,
                                                 ushort* __restrict__ Y_bf) {
    int u = blockIdx.x * 256 + threadIdx.x;            // over elems/2
    int idx = u * 2;
    int n = idx & (NN - 1);
    int o = (idx >> 12) % DD;
    int b = idx / (DD * NN);
    float a0 = 0.f, a1 = 0.f, L0 = 0.f, L1 = 0.f;
    #pragma unroll
    for (int s = 0; s < NSPLIT; ++s) {
        const ushort* Ob = O_bf + ((size_t)(s * BB + b) * DP) * NN + n;
        uint ov = *(const uint*)&Ob[(size_t)o * NN];
        uint lv = *(const uint*)&Ob[(size_t)DD * NN];
        a0 += bf2f_lo(ov); a1 += bf2f_hi(ov);
        L0 += bf2f_lo(lv); L1 += bf2f_hi(lv);
    }
    uint pack = (uint)f2bf_bits(a0 / L0) | ((uint)f2bf_bits(a1 / L1) << 16);
    *(uint*)&Y_bf[idx] = pack;
}

// ---------- K4: out = pixel_shuffle(w_w.Y + w_b) + x, pixel-major, vec2 over w ----------
__global__ __launch_bounds__(256) void k_out(const ushort* __restrict__ Y_bf,
                                             const float* __restrict__ w_w,
                                             const float* __restrict__ w_b,
                                             const float* __restrict__ x,
                                             float* __restrict__ out) {
    __shared__ float ww[DD * DD];
    __shared__ float wb[DD];
    for (int i = threadIdx.x; i < DD * DD; i += 256) ww[i] = w_w[i];
    if (threadIdx.x < DD) wb[threadIdx.x] = w_b[threadIdx.x];
    __syncthreads();
    int u = blockIdx.x * 256 + threadIdx.x;            // over B*TC*H*(W/2)
    int w2 = u & 63;
    int h = (u >> 6) & 127;
    int rest = u >> 13;
    int c1 = rest % TC;
    int b = rest / TC;
    int o0 = c1 * 4 + (h & 1) * 2;                     // wave-uniform
    int n = ((h >> 1) << 6) + w2;
    const ushort* Yb = Y_bf + (size_t)b * DD * NN + n;
    float a0 = wb[o0], a1 = wb[o0 + 1];
    #pragma unroll
    for (int d = 0; d < DD; ++d) {
        float y = bf2f(Yb[(size_t)d * NN]);
        a0 += ww[o0 * DD + d] * y;
        a1 += ww[(o0 + 1) * DD + d] * y;
    }
    size_t xi = ((size_t)(b * TC + c1) * HH + h) * HH + 2 * w2;
    f2v xv = *(const f2v*)&x[xi];
    f2v res = {a0 + xv[0], a1 + xv[1]};
    *(f2v*)&out[xi] = res;
}

extern "C" void kernel_launch(void* const* d_in, const int* in_sizes, int n_in,
                              void* d_out, int out_size, void* d_ws, size_t ws_size,
                              hipStream_t stream) {
    const float* x   = (const float*)d_in[0];
    const float* g_w = (const float*)d_in[1];
    const float* g_b = (const float*)d_in[2];
    const float* w_w = (const float*)d_in[3];
    const float* w_b = (const float*)d_in[4];
    float* out = (float*)d_out;

    char* ws = (char*)d_ws;
    ushort* xf_bf  = (ushort*)ws;                      // 1,966,080 B
    ushort* xf_t   = (ushort*)(ws + 1966080);          // 2,097,152 B
    ushort* G_bf   = (ushort*)(ws + 4063232);          // 1,966,080 B
    float*  rnorm  = (float*)(ws + 6029312);           // 65,536 B
    uint*   mxbits = (uint*)(ws + 6094848);            // 256 B (16 used)
    ushort* O_bf   = (ushort*)(ws + 6095104);          // 16,777,216 B -> end 22,872,320
    const size_t SPLIT_NEED = 22872320;

    hipMemsetAsync(mxbits, 0, BB * sizeof(uint), stream);
    k_prep<<<BB * NN / 256, 256, 0, stream>>>(x, xf_bf, xf_t, rnorm, mxbits);
    k_gproj<<<1920, 256, 0, stream>>>(xf_bf, g_w, g_b, G_bf);

    ushort* Y_bf;
    if (ws_size >= SPLIT_NEED) {
        k_attn<NSPLIT><<<NSPLIT * BB * (NN / QT), 512, 0, stream>>>(
            xf_t, G_bf, rnorm, mxbits, nullptr, O_bf);
        Y_bf = (ushort*)ws;                            // alias xf_bf (dead after attn)
        k_combine<<<1920, 256, 0, stream>>>(O_bf, Y_bf);
    } else {
        Y_bf = (ushort*)(ws + 6095104);
        k_attn<1><<<BB * (NN / QT), 512, 0, stream>>>(
            xf_t, G_bf, rnorm, mxbits, Y_bf, nullptr);
    }
    k_out<<<1920, 256, 0, stream>>>(Y_bf, w_w, w_b, x, out);
}

// Round 18
// 79.217 us; speedup vs baseline: 1.9135x; 1.0116x over previous
//
#include <hip/hip_runtime.h>
#include <hip/hip_bf16.h>

// x: (B=4, T=5, C=3, H=128, W=128) fp32 ; R=2 ; D = 60 ; N = 4096
#define BB 4
#define TC 15
#define DD 60
#define NN 4096
#define HH 128
#define DP 64
#define KT 64
#define NWAVE 4
#define QT 64
#define NTILES 64
#define NSPLIT 8
#define L2E 1.4426950408889634f

typedef short s8v __attribute__((ext_vector_type(8)));   // 8 x bf16
typedef ushort u4v __attribute__((ext_vector_type(4)));
typedef float f4v __attribute__((ext_vector_type(4)));
typedef float f2v __attribute__((ext_vector_type(2)));

static __device__ __forceinline__ ushort f2bf_bits(float f) {
    __hip_bfloat16 h = __float2bfloat16(f);
    return *reinterpret_cast<ushort*>(&h);
}
static __device__ __forceinline__ float bf2f_lo(uint u) { return __uint_as_float(u << 16); }
static __device__ __forceinline__ float bf2f_hi(uint u) { return __uint_as_float(u & 0xFFFF0000u); }
static __device__ __forceinline__ float bf2f(ushort w) { return __uint_as_float((uint)w << 16); }

// ---------- K1: x -> xf_bf (B,D,N) + xf_t (B,N,64) + rnorm + per-batch max norm ----------
__global__ __launch_bounds__(256) void k_prep(const float* __restrict__ x,
                                              ushort* __restrict__ xf_bf,
                                              ushort* __restrict__ xf_t,
                                              float* __restrict__ rnorm,
                                              uint* __restrict__ mxbits) {
    int ng = blockIdx.x * 256 + threadIdx.x;           // b*N + n (blocks never cross b)
    int b = ng >> 12, n = ng & (NN - 1);
    int oh = n >> 6, ow = n & 63;
    const float* xb = x + (size_t)b * TC * HH * HH;
    ushort* xbf = xf_bf + (size_t)b * DD * NN + n;
    ushort row[DP];
    float ss = 0.f;
    #pragma unroll
    for (int d = 0; d < DD; ++d) {
        int c1 = d >> 2, r1 = (d >> 1) & 1, r2 = d & 1;
        float v = xb[(c1 * HH + oh * 2 + r1) * HH + ow * 2 + r2];
        ushort w = f2bf_bits(v);
        row[d] = w;
        float f = bf2f(w);
        ss = fmaf(f, f, ss);
        xbf[(size_t)d * NN] = w;                       // coalesced across lanes
    }
    #pragma unroll
    for (int d = DD; d < DP; ++d) row[d] = 0;
    ushort* dst = xf_t + (size_t)ng * DP;
    #pragma unroll
    for (int j = 0; j < 8; ++j)
        *(s8v*)&dst[j * 8] = *(const s8v*)&row[j * 8];
    float norm = sqrtf(ss) * 1.0002f;                  // safety margin: m must bound row max
    rnorm[ng] = norm;
    float mv = norm;
    #pragma unroll
    for (int off = 1; off < 64; off <<= 1) mv = fmaxf(mv, __shfl_xor(mv, off));
    if ((threadIdx.x & 63) == 0) atomicMax(&mxbits[b], __float_as_uint(mv));
}

// ---------- K2: G (B,D,N) bf16 = g_w . xf + g_b, vec2 along n ----------
__global__ __launch_bounds__(256) void k_gproj(const ushort* __restrict__ xf_bf,
                                               const float* __restrict__ g_w,
                                               const float* __restrict__ g_b,
                                               ushort* __restrict__ G_bf) {
    int u = blockIdx.x * 256 + threadIdx.x;            // over elems/2
    int idx = u * 2;
    int n = idx & (NN - 1);
    int o = (idx >> 12) % DD;                          // block-uniform
    int b = idx / (DD * NN);
    const ushort* X = xf_bf + b * DD * NN;
    float a0 = g_b[o], a1 = a0;
    #pragma unroll
    for (int d = 0; d < DD; ++d) {
        uint w = *(const uint*)&X[d * NN + n];
        float gw = g_w[o * DD + d];
        a0 += gw * bf2f_lo(w);
        a1 += gw * bf2f_hi(w);
    }
    uint pack = (uint)f2bf_bits(a0) | ((uint)f2bf_bits(a1) << 16);
    *(uint*)&G_bf[idx] = pack;
}

// ---------- K3: flash attention, split-K. r17 body (dbuf, single barrier, P/PV
// interleave) at 4 waves/block: P_lds halves -> LDS 40KB -> 4 blocks/CU (vs 3 at
// 48KB), 16 waves/CU. Grid 2048. m_n = rnorm[n]*mxnorm[b] fixed softmax shift;
// l folded into PV via G row 60 == 1.0. ALL NS write unnormalized O_bf (+l col);
// k_cout divides. __launch_bounds__(256,2): 128-VGPR cap (r15: (256,4) capped
// at 64 and can spill); occupancy is LDS-bound at 4 blocks/CU regardless.
template <int NS>
__global__ __launch_bounds__(256, 2) void k_attn(const ushort* __restrict__ xf_t,
                                                 const ushort* __restrict__ G_bf,
                                                 const float* __restrict__ rnorm,
                                                 const uint* __restrict__ mxbits,
                                                 ushort* __restrict__ O_bf) {  // (s,b,64,N) bf16
    __shared__ char K_lds[2][KT * 128];                // 16 KB
    __shared__ char G_lds[2][DP * 128];                // 16 KB
    __shared__ char P_lds[NWAVE][16 * 128];            // 8 KB

    int p = blockIdx.x;
    int s, b, q0;
    if (NS == NSPLIT) {
        // XCD-aware: xcd = p&7; each XCD pair-half owns one batch (4MB = one L2)
        int xcd = p & 7, slot = p >> 3;                // slot in [0,256)
        b = xcd >> 1;
        s = (xcd & 1) * 4 + (slot >> 6);
        q0 = (slot & 63) * QT;
    } else {
        s = 0;
        b = p >> 6;
        q0 = (p & 63) * QT;
    }
    int tid = threadIdx.x;
    int lane = tid & 63, wv = tid >> 6;
    int r = lane & 15, g = lane >> 4;

    const ushort* Xt = xf_t + (size_t)b * NN * DP;
    const ushort* Gb = G_bf + (size_t)b * DD * NN;

    int qrow = q0 + wv * 16 + r;
    s8v qa[2];
    qa[0] = *(const s8v*)&Xt[(size_t)qrow * DP + g * 8];
    qa[1] = *(const s8v*)&Xt[(size_t)qrow * DP + 32 + g * 8];

    // fixed per-row shift, rows 4g+0..3 of this lane
    float mx = __uint_as_float(mxbits[b]);
    float nm[4];
    #pragma unroll
    for (int reg = 0; reg < 4; ++reg)
        nm[reg] = -rnorm[b * NN + q0 + wv * 16 + 4 * g + reg] * mx * L2E;

    f4v of[4];
    #pragma unroll
    for (int i = 0; i < 4; ++i) of[i] = (f4v){0.f, 0.f, 0.f, 0.f};

    // staging: 256 threads x two 16B units per buffer; row = e>>3, j = e&7
    const int e0 = tid, e1 = 256 + tid;
    const int kr0 = e0 >> 3, kj0 = e0 & 7;             // rows 0..31
    const int kr1 = e1 >> 3, kj1 = e1 & 7;             // rows 32..63
    const int kw0 = (kr0 * 128 + kj0 * 16) ^ ((kr0 & 7) << 4);
    const int kw1 = (kr1 * 128 + kj1 * 16) ^ ((kr1 & 7) << 4);
    const s8v ones8 = {(short)0x3F80, (short)0x3F80, (short)0x3F80, (short)0x3F80,
                       (short)0x3F80, (short)0x3F80, (short)0x3F80, (short)0x3F80};
    const s8v zero8 = {0, 0, 0, 0, 0, 0, 0, 0};
    s8v kp0, kp1, gp0, gp1;

    auto stage_regs = [&](int t) {
        int n0 = t * KT;
        kp0 = *(const s8v*)&Xt[(size_t)(n0 + kr0) * DP + kj0 * 8];
        kp1 = *(const s8v*)&Xt[(size_t)(n0 + kr1) * DP + kj1 * 8];
        gp0 = *(const s8v*)&Gb[(size_t)kr0 * NN + n0 + kj0 * 8];   // rows 0..31 < 60
        gp1 = (kr1 < DD) ? *(const s8v*)&Gb[(size_t)kr1 * NN + n0 + kj1 * 8]
                         : (kr1 == DD ? ones8 : zero8);
    };
    auto lds_write = [&](int bu) {
        *(s8v*)(K_lds[bu] + kw0) = kp0;
        *(s8v*)(K_lds[bu] + kw1) = kp1;
        *(s8v*)(G_lds[bu] + kw0) = gp0;
        *(s8v*)(G_lds[bu] + kw1) = gp1;
    };

    const int t0 = s * (NTILES / NS);
    const int tend = t0 + NTILES / NS;
    char* Pw = P_lds[wv];

    stage_regs(t0);
    lds_write(0);
    __syncthreads();

    #pragma unroll 1
    for (int t = t0; t < tend; ++t) {
        const int cur = (t - t0) & 1;
        bool more = (t + 1 < tend);
        if (more) stage_regs(t + 1);          // global loads in flight during compute
        const char* Kc = K_lds[cur];
        const char* Gc = G_lds[cur];

        // ---- S = Q.K^T ----
        f4v sf[4];
        #pragma unroll
        for (int i = 0; i < 4; ++i) sf[i] = (f4v){0.f, 0.f, 0.f, 0.f};
        __builtin_amdgcn_s_setprio(1);
        #pragma unroll
        for (int kt2 = 0; kt2 < 4; ++kt2)
            #pragma unroll
            for (int kb = 0; kb < 2; ++kb) {
                int off = (((kt2 * 16 + r) * 128) + kb * 64 + g * 16) ^ ((r & 7) << 4);
                s8v bf = *(const s8v*)(Kc + off);
                sf[kt2] = __builtin_amdgcn_mfma_f32_16x16x32_bf16(qa[kb], bf, sf[kt2], 0, 0, 0);
            }
        __builtin_amdgcn_s_setprio(0);

        // ---- P for keys 0..31 (kt2 = 0,1) ----
        #pragma unroll
        for (int kt2 = 0; kt2 < 2; ++kt2)
            #pragma unroll
            for (int reg = 0; reg < 4; ++reg) {
                float pv = __builtin_exp2f(fmaf(sf[kt2][reg], L2E, nm[reg]));
                int row = 4 * g + reg;
                int boff = ((row * 128) + kt2 * 32 + 2 * r) ^ ((row & 7) << 4);
                *(ushort*)(Pw + boff) = f2bf_bits(pv);
            }
        // ---- PV kb=0 (wave-internal LDS is in-order; overlaps next P block) ----
        {
            int poff = ((r * 128) + g * 16) ^ ((r & 7) << 4);
            s8v pa = *(const s8v*)(Pw + poff);
            __builtin_amdgcn_s_setprio(1);
            #pragma unroll
            for (int ot = 0; ot < 4; ++ot) {
                int goff = (((ot * 16 + r) * 128) + g * 16) ^ ((r & 7) << 4);
                s8v gf = *(const s8v*)(Gc + goff);
                of[ot] = __builtin_amdgcn_mfma_f32_16x16x32_bf16(pa, gf, of[ot], 0, 0, 0);
            }
            __builtin_amdgcn_s_setprio(0);
        }
        // ---- P for keys 32..63 (kt2 = 2,3) ----
        #pragma unroll
        for (int kt2 = 2; kt2 < 4; ++kt2)
            #pragma unroll
            for (int reg = 0; reg < 4; ++reg) {
                float pv = __builtin_exp2f(fmaf(sf[kt2][reg], L2E, nm[reg]));
                int row = 4 * g + reg;
                int boff = ((row * 128) + kt2 * 32 + 2 * r) ^ ((row & 7) << 4);
                *(ushort*)(Pw + boff) = f2bf_bits(pv);
            }
        // ---- PV kb=1 ----
        {
            int poff = ((r * 128) + 64 + g * 16) ^ ((r & 7) << 4);
            s8v pa = *(const s8v*)(Pw + poff);
            __builtin_amdgcn_s_setprio(1);
            #pragma unroll
            for (int ot = 0; ot < 4; ++ot) {
                int goff = (((ot * 16 + r) * 128) + 64 + g * 16) ^ ((r & 7) << 4);
                s8v gf = *(const s8v*)(Gc + goff);
                of[ot] = __builtin_amdgcn_mfma_f32_16x16x32_bf16(pa, gf, of[ot], 0, 0, 0);
            }
            __builtin_amdgcn_s_setprio(0);
        }

        if (more) lds_write(cur ^ 1);         // write-late into the other buffer
        __syncthreads();                      // single barrier per tile
    }

    // unified epilogue: unnormalized O (+ l in col 60) for all NS; k_cout divides
    int qb = q0 + wv * 16 + 4 * g;
    ushort* Ob = O_bf + ((size_t)(s * BB + b) * DP) * NN;
    #pragma unroll
    for (int ot = 0; ot < 4; ++ot) {
        int o = ot * 16 + r;
        u4v v = {f2bf_bits(of[ot][0]), f2bf_bits(of[ot][1]),
                 f2bf_bits(of[ot][2]), f2bf_bits(of[ot][3])};
        *(u4v*)&Ob[(size_t)o * NN + qb] = v;                 // coalesced 32B per r-group
    }
}

// ---------- K4 (fused combine+out): block per 32 pixels. Phase 1: sum NS splits
// into y_lds[32][61] f32 (stride 61 -> bank-free) + linv from l col (o=60).
// Phase 2: out[o] = (ww[o].y)*linv + wb[o] + x, written pixel-shuffled.
// Replaces k_combine + k_out: kills the Y buffer (2MB write + 60x re-read) + 1 launch.
template <int NS>
__global__ __launch_bounds__(256) void k_cout(const ushort* __restrict__ O_bf,
                                              const float* __restrict__ w_w,
                                              const float* __restrict__ w_b,
                                              const float* __restrict__ x,
                                              float* __restrict__ out) {
    __shared__ float ww[DD * DD];                      // 14.4 KB
    __shared__ float wb[DD];
    __shared__ float ylds[32][61];                     // 7.8 KB
    __shared__ float linv[32];

    int b  = blockIdx.x >> 7;                          // grid = BB*128
    int n0 = (blockIdx.x & 127) * 32;
    int tid = threadIdx.x;
    for (int i = tid; i < DD * DD; i += 256) ww[i] = w_w[i];
    if (tid < DD) wb[tid] = w_b[tid];

    int pix  = tid & 31;
    int ogrp = tid >> 5;                               // 0..7
    int n = n0 + pix;

    // ---- phase 1: y[pix][o] = sum_s O_s[o][n] ; linv[pix] = 1/sum_s O_s[60][n] ----
    const ushort* Op = O_bf + (size_t)b * DP * NN + n;
    #pragma unroll
    for (int i = 0; i < 8; ++i) {
        int o = ogrp * 8 + i;                          // 0..63
        if (o > DD) continue;                          // o<=60 processed
        float sum = 0.f;
        #pragma unroll
        for (int ss = 0; ss < NS; ++ss)
            sum += bf2f(Op[(size_t)ss * BB * DP * NN + (size_t)o * NN]);
        if (o < DD) ylds[pix][o] = sum;
        else        linv[pix] = 1.0f / sum;            // o == 60
    }
    __syncthreads();

    // ---- phase 2: 8 outputs per thread (o = 8k+ogrp), ww from LDS, y from LDS ----
    float li = linv[pix];
    int oh = n >> 6, ow = n & 63;
    #pragma unroll
    for (int k = 0; k < 8; ++k) {
        int o = k * 8 + ogrp;
        if (o < DD) {
            float acc = 0.f;
            #pragma unroll
            for (int d = 0; d < DD; ++d)
                acc = fmaf(ww[o * DD + d], ylds[pix][d], acc);
            int c1 = o >> 2, r1 = (o >> 1) & 1, r2 = o & 1;
            size_t xi = ((size_t)(b * TC + c1) * HH + 2 * oh + r1) * HH + 2 * ow + r2;
            out[xi] = fmaf(acc, li, wb[o]) + x[xi];
        }
    }
}

extern "C" void kernel_launch(void* const* d_in, const int* in_sizes, int n_in,
                              void* d_out, int out_size, void* d_ws, size_t ws_size,
                              hipStream_t stream) {
    const float* x   = (const float*)d_in[0];
    const float* g_w = (const float*)d_in[1];
    const float* g_b = (const float*)d_in[2];
    const float* w_w = (const float*)d_in[3];
    const float* w_b = (const float*)d_in[4];
    float* out = (float*)d_out;

    char* ws = (char*)d_ws;
    ushort* xf_bf  = (ushort*)ws;                      // 1,966,080 B
    ushort* xf_t   = (ushort*)(ws + 1966080);          // 2,097,152 B
    ushort* G_bf   = (ushort*)(ws + 4063232);          // 1,966,080 B
    float*  rnorm  = (float*)(ws + 6029312);           // 65,536 B
    uint*   mxbits = (uint*)(ws + 6094848);            // 256 B (16 used)
    ushort* O_bf   = (ushort*)(ws + 6095104);          // 16,777,216 B -> end 22,872,320
    const size_t SPLIT_NEED = 22872320;

    hipMemsetAsync(mxbits, 0, BB * sizeof(uint), stream);
    k_prep<<<BB * NN / 256, 256, 0, stream>>>(x, xf_bf, xf_t, rnorm, mxbits);
    k_gproj<<<1920, 256, 0, stream>>>(xf_bf, g_w, g_b, G_bf);

    if (ws_size >= SPLIT_NEED) {
        k_attn<NSPLIT><<<NSPLIT * BB * (NN / QT), 256, 0, stream>>>(
            xf_t, G_bf, rnorm, mxbits, O_bf);
        k_cout<NSPLIT><<<BB * 128, 256, 0, stream>>>(O_bf, w_w, w_b, x, out);
    } else {
        k_attn<1><<<BB * (NN / QT), 256, 0, stream>>>(
            xf_t, G_bf, rnorm, mxbits, O_bf);
        k_cout<1><<<BB * 128, 256, 0, stream>>>(O_bf, w_w, w_b, x, out);
    }
}

// Round 19
// 78.788 us; speedup vs baseline: 1.9239x; 1.0054x over previous
//
#include <hip/hip_runtime.h>
#include <hip/hip_bf16.h>

// x: (B=4, T=5, C=3, H=128, W=128) fp32 ; R=2 ; D = 60 ; N = 4096
#define BB 4
#define TC 15
#define DD 60
#define NN 4096
#define HH 128
#define DP 64
#define KT 64
#define NWAVE 4
#define QT 64
#define NTILES 64
#define NSPLIT 8
#define L2E 1.4426950408889634f

typedef short s8v __attribute__((ext_vector_type(8)));   // 8 x bf16
typedef ushort u4v __attribute__((ext_vector_type(4)));
typedef float f4v __attribute__((ext_vector_type(4)));
typedef float f2v __attribute__((ext_vector_type(2)));

static __device__ __forceinline__ ushort f2bf_bits(float f) {
    __hip_bfloat16 h = __float2bfloat16(f);
    return *reinterpret_cast<ushort*>(&h);
}
static __device__ __forceinline__ float bf2f_lo(uint u) { return __uint_as_float(u << 16); }
static __device__ __forceinline__ float bf2f_hi(uint u) { return __uint_as_float(u & 0xFFFF0000u); }
static __device__ __forceinline__ float bf2f(ushort w) { return __uint_as_float((uint)w << 16); }

// ---------- K1: x -> xf_bf (B,D,N) + xf_t (B,N,64) + rnorm + per-batch max norm ----------
__global__ __launch_bounds__(256) void k_prep(const float* __restrict__ x,
                                              ushort* __restrict__ xf_bf,
                                              ushort* __restrict__ xf_t,
                                              float* __restrict__ rnorm,
                                              uint* __restrict__ mxbits) {
    int ng = blockIdx.x * 256 + threadIdx.x;           // b*N + n (blocks never cross b)
    int b = ng >> 12, n = ng & (NN - 1);
    int oh = n >> 6, ow = n & 63;
    const float* xb = x + (size_t)b * TC * HH * HH;
    ushort* xbf = xf_bf + (size_t)b * DD * NN + n;
    ushort row[DP];
    float ss = 0.f;
    #pragma unroll
    for (int d = 0; d < DD; ++d) {
        int c1 = d >> 2, r1 = (d >> 1) & 1, r2 = d & 1;
        float v = xb[(c1 * HH + oh * 2 + r1) * HH + ow * 2 + r2];
        ushort w = f2bf_bits(v);
        row[d] = w;
        float f = bf2f(w);
        ss = fmaf(f, f, ss);
        xbf[(size_t)d * NN] = w;                       // coalesced across lanes
    }
    #pragma unroll
    for (int d = DD; d < DP; ++d) row[d] = 0;
    ushort* dst = xf_t + (size_t)ng * DP;
    #pragma unroll
    for (int j = 0; j < 8; ++j)
        *(s8v*)&dst[j * 8] = *(const s8v*)&row[j * 8];
    float norm = sqrtf(ss) * 1.0002f;                  // safety margin: m must bound row max
    rnorm[ng] = norm;
    float mv = norm;
    #pragma unroll
    for (int off = 1; off < 64; off <<= 1) mv = fmaxf(mv, __shfl_xor(mv, off));
    if ((threadIdx.x & 63) == 0) atomicMax(&mxbits[b], __float_as_uint(mv));
}

// ---------- K2: G (B,D,N) bf16 = g_w . xf + g_b, vec2 along n ----------
__global__ __launch_bounds__(256) void k_gproj(const ushort* __restrict__ xf_bf,
                                               const float* __restrict__ g_w,
                                               const float* __restrict__ g_b,
                                               ushort* __restrict__ G_bf) {
    int u = blockIdx.x * 256 + threadIdx.x;            // over elems/2
    int idx = u * 2;
    int n = idx & (NN - 1);
    int o = (idx >> 12) % DD;                          // block-uniform
    int b = idx / (DD * NN);
    const ushort* X = xf_bf + b * DD * NN;
    float a0 = g_b[o], a1 = a0;
    #pragma unroll
    for (int d = 0; d < DD; ++d) {
        uint w = *(const uint*)&X[d * NN + n];
        float gw = g_w[o * DD + d];
        a0 += gw * bf2f_lo(w);
        a1 += gw * bf2f_hi(w);
    }
    uint pack = (uint)f2bf_bits(a0) | ((uint)f2bf_bits(a1) << 16);
    *(uint*)&G_bf[idx] = pack;
}

// ---------- K3: flash attention, split-K. SINGLE K/G buffer: LDS 24KB -> 6 blocks/CU
// (vs 40KB dbuf -> 3-4). r11 measured dbuf as neutral; at 6 resident blocks the
// 2-barriers-per-tile cost is covered by the other 5 blocks. Occupancy experiment:
// if OccupancyPercent stays ~31%, residency is NOT the cap -> pivot.
// m_n = rnorm[n]*mxnorm[b] fixed softmax shift; l folded via G row 60 == 1.0.
// ALL NS write unnormalized O_bf (+l col); k_cout divides.
template <int NS>
__global__ __launch_bounds__(256, 2) void k_attn(const ushort* __restrict__ xf_t,
                                                 const ushort* __restrict__ G_bf,
                                                 const float* __restrict__ rnorm,
                                                 const uint* __restrict__ mxbits,
                                                 ushort* __restrict__ O_bf) {  // (s,b,64,N) bf16
    __shared__ char K_lds[KT * 128];                   // 8 KB
    __shared__ char G_lds[DP * 128];                   // 8 KB
    __shared__ char P_lds[NWAVE][16 * 128];            // 8 KB

    int p = blockIdx.x;
    int s, b, q0;
    if (NS == NSPLIT) {
        // XCD-aware: xcd = p&7; each XCD pair-half owns one batch (4MB = one L2)
        int xcd = p & 7, slot = p >> 3;                // slot in [0,256)
        b = xcd >> 1;
        s = (xcd & 1) * 4 + (slot >> 6);
        q0 = (slot & 63) * QT;
    } else {
        s = 0;
        b = p >> 6;
        q0 = (p & 63) * QT;
    }
    int tid = threadIdx.x;
    int lane = tid & 63, wv = tid >> 6;
    int r = lane & 15, g = lane >> 4;

    const ushort* Xt = xf_t + (size_t)b * NN * DP;
    const ushort* Gb = G_bf + (size_t)b * DD * NN;

    int qrow = q0 + wv * 16 + r;
    s8v qa[2];
    qa[0] = *(const s8v*)&Xt[(size_t)qrow * DP + g * 8];
    qa[1] = *(const s8v*)&Xt[(size_t)qrow * DP + 32 + g * 8];

    // fixed per-row shift, rows 4g+0..3 of this lane
    float mx = __uint_as_float(mxbits[b]);
    float nm[4];
    #pragma unroll
    for (int reg = 0; reg < 4; ++reg)
        nm[reg] = -rnorm[b * NN + q0 + wv * 16 + 4 * g + reg] * mx * L2E;

    f4v of[4];
    #pragma unroll
    for (int i = 0; i < 4; ++i) of[i] = (f4v){0.f, 0.f, 0.f, 0.f};

    // staging: 256 threads x two 16B units per buffer; row = e>>3, j = e&7
    const int e0 = tid, e1 = 256 + tid;
    const int kr0 = e0 >> 3, kj0 = e0 & 7;             // rows 0..31
    const int kr1 = e1 >> 3, kj1 = e1 & 7;             // rows 32..63
    const int kw0 = (kr0 * 128 + kj0 * 16) ^ ((kr0 & 7) << 4);
    const int kw1 = (kr1 * 128 + kj1 * 16) ^ ((kr1 & 7) << 4);
    const s8v ones8 = {(short)0x3F80, (short)0x3F80, (short)0x3F80, (short)0x3F80,
                       (short)0x3F80, (short)0x3F80, (short)0x3F80, (short)0x3F80};
    const s8v zero8 = {0, 0, 0, 0, 0, 0, 0, 0};
    s8v kp0, kp1, gp0, gp1;

    auto stage_regs = [&](int t) {
        int n0 = t * KT;
        kp0 = *(const s8v*)&Xt[(size_t)(n0 + kr0) * DP + kj0 * 8];
        kp1 = *(const s8v*)&Xt[(size_t)(n0 + kr1) * DP + kj1 * 8];
        gp0 = *(const s8v*)&Gb[(size_t)kr0 * NN + n0 + kj0 * 8];   // rows 0..31 < 60
        gp1 = (kr1 < DD) ? *(const s8v*)&Gb[(size_t)kr1 * NN + n0 + kj1 * 8]
                         : (kr1 == DD ? ones8 : zero8);
    };
    auto lds_write = [&]() {
        *(s8v*)(K_lds + kw0) = kp0;
        *(s8v*)(K_lds + kw1) = kp1;
        *(s8v*)(G_lds + kw0) = gp0;
        *(s8v*)(G_lds + kw1) = gp1;
    };

    const int t0 = s * (NTILES / NS);
    const int tend = t0 + NTILES / NS;
    char* Pw = P_lds[wv];

    stage_regs(t0);
    lds_write();
    __syncthreads();

    #pragma unroll 1
    for (int t = t0; t < tend; ++t) {
        bool more = (t + 1 < tend);
        if (more) stage_regs(t + 1);          // global loads in flight during compute

        // ---- S = Q.K^T ----
        f4v sf[4];
        #pragma unroll
        for (int i = 0; i < 4; ++i) sf[i] = (f4v){0.f, 0.f, 0.f, 0.f};
        __builtin_amdgcn_s_setprio(1);
        #pragma unroll
        for (int kt2 = 0; kt2 < 4; ++kt2)
            #pragma unroll
            for (int kb = 0; kb < 2; ++kb) {
                int off = (((kt2 * 16 + r) * 128) + kb * 64 + g * 16) ^ ((r & 7) << 4);
                s8v bf = *(const s8v*)(K_lds + off);
                sf[kt2] = __builtin_amdgcn_mfma_f32_16x16x32_bf16(qa[kb], bf, sf[kt2], 0, 0, 0);
            }
        __builtin_amdgcn_s_setprio(0);

        // ---- P for keys 0..31 (kt2 = 0,1) ----
        #pragma unroll
        for (int kt2 = 0; kt2 < 2; ++kt2)
            #pragma unroll
            for (int reg = 0; reg < 4; ++reg) {
                float pv = __builtin_exp2f(fmaf(sf[kt2][reg], L2E, nm[reg]));
                int row = 4 * g + reg;
                int boff = ((row * 128) + kt2 * 32 + 2 * r) ^ ((row & 7) << 4);
                *(ushort*)(Pw + boff) = f2bf_bits(pv);
            }
        // ---- PV kb=0 (wave-internal LDS is in-order; overlaps next P block) ----
        {
            int poff = ((r * 128) + g * 16) ^ ((r & 7) << 4);
            s8v pa = *(const s8v*)(Pw + poff);
            __builtin_amdgcn_s_setprio(1);
            #pragma unroll
            for (int ot = 0; ot < 4; ++ot) {
                int goff = (((ot * 16 + r) * 128) + g * 16) ^ ((r & 7) << 4);
                s8v gf = *(const s8v*)(G_lds + goff);
                of[ot] = __builtin_amdgcn_mfma_f32_16x16x32_bf16(pa, gf, of[ot], 0, 0, 0);
            }
            __builtin_amdgcn_s_setprio(0);
        }
        // ---- P for keys 32..63 (kt2 = 2,3) ----
        #pragma unroll
        for (int kt2 = 2; kt2 < 4; ++kt2)
            #pragma unroll
            for (int reg = 0; reg < 4; ++reg) {
                float pv = __builtin_exp2f(fmaf(sf[kt2][reg], L2E, nm[reg]));
                int row = 4 * g + reg;
                int boff = ((row * 128) + kt2 * 32 + 2 * r) ^ ((row & 7) << 4);
                *(ushort*)(Pw + boff) = f2bf_bits(pv);
            }
        // ---- PV kb=1 ----
        {
            int poff = ((r * 128) + 64 + g * 16) ^ ((r & 7) << 4);
            s8v pa = *(const s8v*)(Pw + poff);
            __builtin_amdgcn_s_setprio(1);
            #pragma unroll
            for (int ot = 0; ot < 4; ++ot) {
                int goff = (((ot * 16 + r) * 128) + 64 + g * 16) ^ ((r & 7) << 4);
                s8v gf = *(const s8v*)(G_lds + goff);
                of[ot] = __builtin_amdgcn_mfma_f32_16x16x32_bf16(pa, gf, of[ot], 0, 0, 0);
            }
            __builtin_amdgcn_s_setprio(0);
        }

        if (more) {
            __syncthreads();                  // all waves done reading K/G
            lds_write();
            __syncthreads();                  // next tile staged
        }
    }

    // unified epilogue: unnormalized O (+ l in col 60) for all NS; k_cout divides
    int qb = q0 + wv * 16 + 4 * g;
    ushort* Ob = O_bf + ((size_t)(s * BB + b) * DP) * NN;
    #pragma unroll
    for (int ot = 0; ot < 4; ++ot) {
        int o = ot * 16 + r;
        u4v v = {f2bf_bits(of[ot][0]), f2bf_bits(of[ot][1]),
                 f2bf_bits(of[ot][2]), f2bf_bits(of[ot][3])};
        *(u4v*)&Ob[(size_t)o * NN + qb] = v;                 // coalesced 32B per r-group
    }
}

// ---------- K4 (fused combine+out): block per 32 pixels. Phase 1: sum NS splits
// into y_lds[32][61] f32 (stride 61 -> bank-free) + linv from l col (o=60).
// Phase 2: out[o] = (ww[o].y)*linv + wb[o] + x, written pixel-shuffled.
template <int NS>
__global__ __launch_bounds__(256) void k_cout(const ushort* __restrict__ O_bf,
                                              const float* __restrict__ w_w,
                                              const float* __restrict__ w_b,
                                              const float* __restrict__ x,
                                              float* __restrict__ out) {
    __shared__ float ww[DD * DD];                      // 14.4 KB
    __shared__ float wb[DD];
    __shared__ float ylds[32][61];                     // 7.8 KB
    __shared__ float linv[32];

    int b  = blockIdx.x >> 7;                          // grid = BB*128
    int n0 = (blockIdx.x & 127) * 32;
    int tid = threadIdx.x;
    for (int i = tid; i < DD * DD; i += 256) ww[i] = w_w[i];
    if (tid < DD) wb[tid] = w_b[tid];

    int pix  = tid & 31;
    int ogrp = tid >> 5;                               // 0..7
    int n = n0 + pix;

    // ---- phase 1: y[pix][o] = sum_s O_s[o][n] ; linv[pix] = 1/sum_s O_s[60][n] ----
    const ushort* Op = O_bf + (size_t)b * DP * NN + n;
    #pragma unroll
    for (int i = 0; i < 8; ++i) {
        int o = ogrp * 8 + i;                          // 0..63
        if (o > DD) continue;                          // o<=60 processed
        float sum = 0.f;
        #pragma unroll
        for (int ss = 0; ss < NS; ++ss)
            sum += bf2f(Op[(size_t)ss * BB * DP * NN + (size_t)o * NN]);
        if (o < DD) ylds[pix][o] = sum;
        else        linv[pix] = 1.0f / sum;            // o == 60
    }
    __syncthreads();

    // ---- phase 2: 8 outputs per thread (o = 8k+ogrp), ww from LDS, y from LDS ----
    float li = linv[pix];
    int oh = n >> 6, ow = n & 63;
    #pragma unroll
    for (int k = 0; k < 8; ++k) {
        int o = k * 8 + ogrp;
        if (o < DD) {
            float acc = 0.f;
            #pragma unroll
            for (int d = 0; d < DD; ++d)
                acc = fmaf(ww[o * DD + d], ylds[pix][d], acc);
            int c1 = o >> 2, r1 = (o >> 1) & 1, r2 = o & 1;
            size_t xi = ((size_t)(b * TC + c1) * HH + 2 * oh + r1) * HH + 2 * ow + r2;
            out[xi] = fmaf(acc, li, wb[o]) + x[xi];
        }
    }
}

extern "C" void kernel_launch(void* const* d_in, const int* in_sizes, int n_in,
                              void* d_out, int out_size, void* d_ws, size_t ws_size,
                              hipStream_t stream) {
    const float* x   = (const float*)d_in[0];
    const float* g_w = (const float*)d_in[1];
    const float* g_b = (const float*)d_in[2];
    const float* w_w = (const float*)d_in[3];
    const float* w_b = (const float*)d_in[4];
    float* out = (float*)d_out;

    char* ws = (char*)d_ws;
    ushort* xf_bf  = (ushort*)ws;                      // 1,966,080 B
    ushort* xf_t   = (ushort*)(ws + 1966080);          // 2,097,152 B
    ushort* G_bf   = (ushort*)(ws + 4063232);          // 1,966,080 B
    float*  rnorm  = (float*)(ws + 6029312);           // 65,536 B
    uint*   mxbits = (uint*)(ws + 6094848);            // 256 B (16 used)
    ushort* O_bf   = (ushort*)(ws + 6095104);          // 16,777,216 B -> end 22,872,320
    const size_t SPLIT_NEED = 22872320;

    hipMemsetAsync(mxbits, 0, BB * sizeof(uint), stream);
    k_prep<<<BB * NN / 256, 256, 0, stream>>>(x, xf_bf, xf_t, rnorm, mxbits);
    k_gproj<<<1920, 256, 0, stream>>>(xf_bf, g_w, g_b, G_bf);

    if (ws_size >= SPLIT_NEED) {
        k_attn<NSPLIT><<<NSPLIT * BB * (NN / QT), 256, 0, stream>>>(
            xf_t, G_bf, rnorm, mxbits, O_bf);
        k_cout<NSPLIT><<<BB * 128, 256, 0, stream>>>(O_bf, w_w, w_b, x, out);
    } else {
        k_attn<1><<<BB * (NN / QT), 256, 0, stream>>>(
            xf_t, G_bf, rnorm, mxbits, O_bf);
        k_cout<1><<<BB * 128, 256, 0, stream>>>(O_bf, w_w, w_b, x, out);
    }
}